// Round 5
// baseline (900.611 us; speedup 1.0000x reference)
//
#include <hip/hip_runtime.h>
#include <hip/hip_fp16.h>

// DNCClassifier: DNC memory machinery is dead code (inputs built with the
// initial zero read vector); output = LSTM-final-h @ W_fc.T + b_fc.
//   gates_t = x_t @ W_ih[:, :27].T + (b_ih + b_hh) + h @ W_hh.T
// Sizes: B=128, T=512, IN=27, H=256 (4H=1024), OUT=128.
//
// R5: VGPR allocation tracks LDS-derived occupancy (R1: 54.8KB->2blk/CU->
// 2waves/SIMD->256 VGPR; R2-R4: 63.5KB->2blk/CU(512thr)->4waves/SIMD->128
// VGPR, attributes ignored). Fix: static LDS > 80 KiB -> 1 block/CU ->
// 8 waves/CU = 2/SIMD -> 256-VGPR budget, no remat incentive.
// Tiers (64 weight quads/thread): 52 VGPR (208 regs), 8 LDS (64 KB/step
// reads, ~750 cyc on 85 B/cyc pipe, overlaps 1024-cyc dot issue),
// 4 streamed (32 KB region == L1-resident).
// Flat weight-quad id f = q*4+g (q = h-quad 0..15 in K-half, g = gate):
// f<52 VGPR, 52..59 LDS, 60..63 streamed. k2=(v>>8)*64+4q+e, row=g*256+(v&255).

typedef _Float16 h2t __attribute__((ext_vector_type(2)));
typedef unsigned int u32x4 __attribute__((ext_vector_type(4)));

#if defined(__has_builtin)
#  if __has_builtin(__builtin_amdgcn_fdot2)
#    define HAVE_FDOT2 1
#  endif
#endif

__device__ __forceinline__ h2t bc2(unsigned int v) {
  union { unsigned int u; h2t h; } x; x.u = v; return x.h;
}
__device__ __forceinline__ unsigned int pk(float a, float b) {
  union { h2t h; unsigned int u; } x;
  x.h[0] = (_Float16)a; x.h[1] = (_Float16)b;
  return x.u;
}
__device__ __forceinline__ float fdot2f(h2t a, h2t b, float c) {
#ifdef HAVE_FDOT2
  return __builtin_amdgcn_fdot2(a, b, c, false);
#else
  return c + (float)a[0] * (float)b[0] + (float)a[1] * (float)b[1];
#endif
}
__device__ __forceinline__ float dot4(u32x4 w, u32x4 h, float a) {
  a = fdot2f(bc2(w[0]), bc2(h[0]), a);
  a = fdot2f(bc2(w[1]), bc2(h[1]), a);
  a = fdot2f(bc2(w[2]), bc2(h[2]), a);
  a = fdot2f(bc2(w[3]), bc2(h[3]), a);
  return a;
}
__device__ __forceinline__ float sigmf_(float x) {
  return 1.f / (1.f + __expf(-x));
}
__device__ __forceinline__ float tanhf_(float x) {
  float xc = fminf(15.f, fmaxf(-15.f, x));
  float e = __expf(2.f * xc);
  return (e - 1.f) / (e + 1.f);
}

// ---- workspace layout (bytes) ----
// P      : [(t*128+b)*256+u] uint2 (gates i,f,g,o fp16, bias folded in)
// Wscan  : u32x4[f *512+v], f  = 0..51           -> VGPR-resident
// Wlds   : u32x4[fl*512+v], fl = f-52, f = 52..59 -> LDS-resident
// Wstr   : u32x4[fs*512+v], fs = f-60, f = 60..63 -> streamed (L1-resident)
#define WS_P_OFF      0ull
#define WS_WSCAN_OFF  134217728ull   // 52*512*16 = 425984
#define WS_WLDS_OFF   134643712ull   // 8*512*16  = 65536
#define WS_WSTR_OFF   134709248ull   // 4*512*16  = 32768
#define WS_NEED       134742016ull

__global__ void prep_w(const float* __restrict__ W_hh,
                       unsigned char* __restrict__ ws) {
  int idx = blockIdx.x * 256 + threadIdx.x;   // 512 blocks -> idx < 131072
  unsigned int* dst; int j, f;
  if (idx < 106496) {                         // Wscan: 52*512*4 uints
    j = idx; dst = (unsigned int*)(ws + WS_WSCAN_OFF); f = (j >> 2) >> 9;
  } else if (idx < 122880) {                  // Wlds: 8*512*4 uints
    j = idx - 106496; dst = (unsigned int*)(ws + WS_WLDS_OFF);
    f = 52 + ((j >> 2) >> 9);
  } else {                                    // Wstr: 4*512*4 uints
    j = idx - 122880; dst = (unsigned int*)(ws + WS_WSTR_OFF);
    f = 60 + ((j >> 2) >> 9);
  }
  int e = j & 3, v = (j >> 2) & 511;
  int q = f >> 2, g = f & 3;
  int k2 = ((v >> 8) << 6) + 4 * q + e;
  int r = g * 256 + (v & 255);
  dst[j] = pk(W_hh[r * 256 + 2 * k2], W_hh[r * 256 + 2 * k2 + 1]);
}

// P[t,b,u,:] = bias(u,:) + x[b,t,:27] @ W_ih[:, :27].T  (fp16x4 out)
// grid 1024: block handles one t (= blockIdx>>1) x 64 b's. x staged up front.
__global__ __launch_bounds__(256) void prep_p(const float* __restrict__ x,
                                              const float* __restrict__ W_ih,
                                              const float* __restrict__ b_ih,
                                              const float* __restrict__ b_hh,
                                              unsigned char* __restrict__ ws) {
  __shared__ unsigned int sX[64][14];
  const int u = threadIdx.x;
  const int t = blockIdx.x >> 1;
  const int b0 = (blockIdx.x & 1) << 6;
  unsigned int wih[4][14];
  float bias[4];
#pragma unroll
  for (int g = 0; g < 4; ++g) {
    const float* row = W_ih + (size_t)(g * 256 + u) * 47;
    bias[g] = b_ih[g * 256 + u] + b_hh[g * 256 + u];
#pragma unroll
    for (int j = 0; j < 14; ++j) {
      float a = row[2 * j];
      float b = (2 * j + 1 < 27) ? row[2 * j + 1] : 0.f;
      wih[g][j] = pk(a, b);
    }
  }
#pragma unroll 1
  for (int j = u; j < 896; j += 256) {        // stage 64 rows of x
    int row = j / 14, c2 = j - 14 * row;
    const float* xr = x + ((size_t)(b0 + row) * 512 + t) * 27;
    float a = xr[2 * c2];
    float bb = (2 * c2 + 1 < 27) ? xr[2 * c2 + 1] : 0.f;
    sX[row][c2] = pk(a, bb);
  }
  __syncthreads();
  uint2* Pout = (uint2*)(ws + WS_P_OFF);
#pragma unroll 2
  for (int p = 0; p < 64; ++p) {
    float a0 = bias[0], a1 = bias[1], a2 = bias[2], a3 = bias[3];
#pragma unroll
    for (int j = 0; j < 14; ++j) {
      h2t xx = bc2(sX[p][j]);
      a0 = fdot2f(bc2(wih[0][j]), xx, a0);
      a1 = fdot2f(bc2(wih[1][j]), xx, a1);
      a2 = fdot2f(bc2(wih[2][j]), xx, a2);
      a3 = fdot2f(bc2(wih[3][j]), xx, a3);
    }
    uint2 o; o.x = pk(a0, a1); o.y = pk(a2, a3);
    Pout[((size_t)t * 128 + (b0 + p)) * 256 + u] = o;
  }
}

// Persistent LSTM scan. grid=128 (one block per batch element), 512 threads.
// Static LDS ~84 KB forces 1 block/CU -> 2 waves/SIMD -> 256-VGPR budget.
__global__ __launch_bounds__(512, 2) void scan_k(
    const unsigned char* __restrict__ ws, const float* __restrict__ W_fc,
    const float* __restrict__ b_fc, float* __restrict__ out) {
  __shared__ u32x4 sWq[8 * 512];               // 65,536 B LDS-resident weights
  __shared__ u32x4 sHq[2][32];                 // h double buffer (128 h2)
  __shared__ float4 sAcc[256];                 // high->low partial exchange
  __shared__ float sHF[256];                   // final h fp32 for head
  __shared__ u32x4 sPad[768];                  // 12,288 B occupancy clamp:
                                               // total LDS 84 KB > 80 KB
                                               // -> exactly 1 block/CU
  const int v = threadIdx.x;
  const int b = blockIdx.x;
  const int half = v >> 8;
  const int u = v & 255;

  // --- tier 1: VGPR-resident weights (52 quads = 208 regs) ---
  u32x4 wr[52];
  {
    const u32x4* wsc = (const u32x4*)(ws + WS_WSCAN_OFF);
#pragma unroll
    for (int f = 0; f < 52; ++f) wr[f] = wsc[f * 512 + v];
  }
  // --- tier 2: LDS-resident weights (8 quads) ---
  {
    const u32x4* wld = (const u32x4*)(ws + WS_WLDS_OFF);
#pragma unroll
    for (int fl = 0; fl < 8; ++fl) sWq[fl * 512 + v] = wld[fl * 512 + v];
  }
  const u32x4* wstr = (const u32x4*)(ws + WS_WSTR_OFF);

  if (v < 64) {
    u32x4 z = {0u, 0u, 0u, 0u};
    ((u32x4*)sHq)[v] = z;                      // both h buffers = 0
  }
  const uint2* Pbuf = (const uint2*)(ws + WS_P_OFF);
  uint2 pP = make_uint2(0u, 0u);
  if (half == 0) pP = Pbuf[(size_t)b * 256 + u];
  float c = 0.f, hval = 0.f;
  __syncthreads();

#pragma unroll 1
  for (int t = 0; t < 512; ++t) {
    // --- tier 3: streamed weights (4 quads, 32 KB region, L1-resident) ---
    u32x4 tw0 = wstr[0 * 512 + v];
    u32x4 tw1 = wstr[1 * 512 + v];
    u32x4 tw2 = wstr[2 * 512 + v];
    u32x4 tw3 = wstr[3 * 512 + v];

    const u32x4* rd = &sHq[t & 1][half << 4];
    float acc0 = 0.f, acc1 = 0.f, acc2 = 0.f, acc3 = 0.f;
#pragma unroll
    for (int q = 0; q < 13; ++q) {             // f = 4q+g < 52: VGPR tier
      u32x4 hq = rd[q];
      acc0 = dot4(wr[q * 4 + 0], hq, acc0);
      acc1 = dot4(wr[q * 4 + 1], hq, acc1);
      acc2 = dot4(wr[q * 4 + 2], hq, acc2);
      acc3 = dot4(wr[q * 4 + 3], hq, acc3);
    }
    {  // q=13: f=52..55 LDS
      u32x4 hq = rd[13];
      acc0 = dot4(sWq[0 * 512 + v], hq, acc0);
      acc1 = dot4(sWq[1 * 512 + v], hq, acc1);
      acc2 = dot4(sWq[2 * 512 + v], hq, acc2);
      acc3 = dot4(sWq[3 * 512 + v], hq, acc3);
    }
    {  // q=14: f=56..59 LDS
      u32x4 hq = rd[14];
      acc0 = dot4(sWq[4 * 512 + v], hq, acc0);
      acc1 = dot4(sWq[5 * 512 + v], hq, acc1);
      acc2 = dot4(sWq[6 * 512 + v], hq, acc2);
      acc3 = dot4(sWq[7 * 512 + v], hq, acc3);
    }
    {  // q=15: f=60..63 streamed
      u32x4 hq = rd[15];
      acc0 = dot4(tw0, hq, acc0);
      acc1 = dot4(tw1, hq, acc1);
      acc2 = dot4(tw2, hq, acc2);
      acc3 = dot4(tw3, hq, acc3);
    }

    uint2 pPn = pP;
    if (half) {
      sAcc[u] = make_float4(acc0, acc1, acc2, acc3);
    } else {
      int tn = (t < 511) ? (t + 1) : 511;
      pPn = Pbuf[((size_t)tn * 128 + b) * 256 + u];
    }
    __syncthreads();                           // sAcc visible; sH reads done

    if (!half) {
      float4 oth = sAcc[u];
      h2t p01 = bc2(pP.x), p23 = bc2(pP.y);
      float gi = acc0 + oth.x + (float)p01[0];
      float gf = acc1 + oth.y + (float)p01[1];
      float gg = acc2 + oth.z + (float)p23[0];
      float go = acc3 + oth.w + (float)p23[1];
      c = sigmf_(gf) * c + sigmf_(gi) * tanhf_(gg);
      hval = sigmf_(go) * tanhf_(c);
      ((_Float16*)(&sHq[(t + 1) & 1][0]))[u] = (_Float16)hval;
    }
    pP = pPn;
    __syncthreads();                           // h_{t+1} visible
  }

  // keep sPad alive without ever touching it (b < 128 always)
  if (b == 0x7fffffff) sPad[v & 767] = wr[0];

  // --- classifier head on final h ---
  if (!half) sHF[u] = hval;
  __syncthreads();
  if (v < 128) {
    const float4* wrow = (const float4*)(W_fc + (size_t)v * 256);
    float a = b_fc[v];
#pragma unroll 8
    for (int q = 0; q < 64; ++q) {
      float4 w = wrow[q];
      float4 hh = ((const float4*)sHF)[q];
      a += w.x * hh.x + w.y * hh.y + w.z * hh.z + w.w * hh.w;
    }
    out[(size_t)b * 128 + v] = a;
  }
}

extern "C" void kernel_launch(void* const* d_in, const int* in_sizes, int n_in,
                              void* d_out, int out_size, void* d_ws,
                              size_t ws_size, hipStream_t stream) {
  const float* x    = (const float*)d_in[0];
  // d_in[1] = input_lengths: unused by the reference
  const float* W_ih = (const float*)d_in[2];
  const float* W_hh = (const float*)d_in[3];
  const float* b_ih = (const float*)d_in[4];
  const float* b_hh = (const float*)d_in[5];
  // d_in[6] = W_xi, d_in[7] = b_xi: dead code in the reference
  const float* W_fc = (const float*)d_in[8];
  const float* b_fc = (const float*)d_in[9];
  unsigned char* ws = (unsigned char*)d_ws;

  if (ws_size < WS_NEED) return;  // signature: output stays poisoned

  prep_w<<<512, 256, 0, stream>>>(W_hh, ws);
  prep_p<<<1024, 256, 0, stream>>>(x, W_ih, b_ih, b_hh, ws);
  scan_k<<<128, 512, 0, stream>>>(ws, W_fc, b_fc, (float*)d_out);
}

// Round 6
// 871.343 us; speedup vs baseline: 1.0336x; 1.0336x over previous
//
#include <hip/hip_runtime.h>
#include <hip/hip_fp16.h>

// DNCClassifier: DNC memory machinery is dead code (inputs built with the
// initial zero read vector); output = LSTM-final-h @ W_fc.T + b_fc.
//   gates_t = x_t @ W_ih[:, :27].T + (b_ih + b_hh) + h @ W_hh.T
// Sizes: B=128, T=512, IN=27, H=256 (4H=1024), OUT=128.
//
// R6: empirical rule from R1-R5: VGPR budget = 512 / (waves-per-SIMD that the
// compiler derives from STATIC LDS + block size). R5's LDS pad was DCE'd
// (71680 B <= 81920 -> 2 blk/CU -> 4 waves/SIMD -> 128 VGPR + accvgpr spill,
// ~1450 cyc/step of accvgpr_read traffic). Fix: grow the LDS weight tier to
// 80 KB (productive, not a pad) -> static 86 KB > 80 KB -> 1 blk/CU ->
// 2 waves/SIMD -> 256 arch VGPRs. Only 128 workgroups exist on 256 CUs, so
// real residency was always 1 blk/CU; this only fixes the compiler's budget.
// Tiers (64 weight quads/thread): 52 VGPR (208 regs), 10 LDS (80 KB/step
// reads, ~940 cyc on ~85 B/cyc pipe, overlaps the 1024-cyc dot issue),
// 2 streamed (16 KB region == L1-resident).
// Flat weight-quad id f = q*4+g (q = h-quad 0..15 in K-half, g = gate):
// f<52 VGPR, 52..61 LDS, 62..63 streamed. k2=(v>>8)*64+4q+e, row=g*256+(v&255).

typedef _Float16 h2t __attribute__((ext_vector_type(2)));
typedef unsigned int u32x4 __attribute__((ext_vector_type(4)));

#if defined(__has_builtin)
#  if __has_builtin(__builtin_amdgcn_fdot2)
#    define HAVE_FDOT2 1
#  endif
#endif

__device__ __forceinline__ h2t bc2(unsigned int v) {
  union { unsigned int u; h2t h; } x; x.u = v; return x.h;
}
__device__ __forceinline__ unsigned int pk(float a, float b) {
  union { h2t h; unsigned int u; } x;
  x.h[0] = (_Float16)a; x.h[1] = (_Float16)b;
  return x.u;
}
__device__ __forceinline__ float fdot2f(h2t a, h2t b, float c) {
#ifdef HAVE_FDOT2
  return __builtin_amdgcn_fdot2(a, b, c, false);
#else
  return c + (float)a[0] * (float)b[0] + (float)a[1] * (float)b[1];
#endif
}
__device__ __forceinline__ float dot4(u32x4 w, u32x4 h, float a) {
  a = fdot2f(bc2(w[0]), bc2(h[0]), a);
  a = fdot2f(bc2(w[1]), bc2(h[1]), a);
  a = fdot2f(bc2(w[2]), bc2(h[2]), a);
  a = fdot2f(bc2(w[3]), bc2(h[3]), a);
  return a;
}
__device__ __forceinline__ float sigmf_(float x) {
  return 1.f / (1.f + __expf(-x));
}
__device__ __forceinline__ float tanhf_(float x) {
  float xc = fminf(15.f, fmaxf(-15.f, x));
  float e = __expf(2.f * xc);
  return (e - 1.f) / (e + 1.f);
}

// ---- workspace layout (bytes) ----
// P      : [(t*128+b)*256+u] uint2 (gates i,f,g,o fp16, bias folded in)
// Wscan  : u32x4[f *512+v], f  = 0..51            -> VGPR-resident
// Wlds   : u32x4[fl*512+v], fl = f-52, f = 52..61 -> LDS-resident
// Wstr   : u32x4[fs*512+v], fs = f-62, f = 62..63 -> streamed (L1-resident)
#define WS_P_OFF      0ull
#define WS_WSCAN_OFF  134217728ull   // 52*512*16 = 425984
#define WS_WLDS_OFF   134643712ull   // 10*512*16 = 81920
#define WS_WSTR_OFF   134725632ull   // 2*512*16  = 16384
#define WS_NEED       134742016ull

__global__ void prep_w(const float* __restrict__ W_hh,
                       unsigned char* __restrict__ ws) {
  int idx = blockIdx.x * 256 + threadIdx.x;   // 512 blocks -> idx < 131072
  unsigned int* dst; int j, f;
  if (idx < 106496) {                         // Wscan: 52*512*4 uints
    j = idx; dst = (unsigned int*)(ws + WS_WSCAN_OFF); f = (j >> 2) >> 9;
  } else if (idx < 126976) {                  // Wlds: 10*512*4 uints
    j = idx - 106496; dst = (unsigned int*)(ws + WS_WLDS_OFF);
    f = 52 + ((j >> 2) >> 9);
  } else {                                    // Wstr: 2*512*4 uints
    j = idx - 126976; dst = (unsigned int*)(ws + WS_WSTR_OFF);
    f = 62 + ((j >> 2) >> 9);
  }
  int e = j & 3, v = (j >> 2) & 511;
  int q = f >> 2, g = f & 3;
  int k2 = ((v >> 8) << 6) + 4 * q + e;
  int r = g * 256 + (v & 255);
  dst[j] = pk(W_hh[r * 256 + 2 * k2], W_hh[r * 256 + 2 * k2 + 1]);
}

// P[t,b,u,:] = bias(u,:) + x[b,t,:27] @ W_ih[:, :27].T  (fp16x4 out)
// grid 1024: block handles one t (= blockIdx>>1) x 64 b's. x staged up front.
__global__ __launch_bounds__(256) void prep_p(const float* __restrict__ x,
                                              const float* __restrict__ W_ih,
                                              const float* __restrict__ b_ih,
                                              const float* __restrict__ b_hh,
                                              unsigned char* __restrict__ ws) {
  __shared__ unsigned int sX[64][14];
  const int u = threadIdx.x;
  const int t = blockIdx.x >> 1;
  const int b0 = (blockIdx.x & 1) << 6;
  unsigned int wih[4][14];
  float bias[4];
#pragma unroll
  for (int g = 0; g < 4; ++g) {
    const float* row = W_ih + (size_t)(g * 256 + u) * 47;
    bias[g] = b_ih[g * 256 + u] + b_hh[g * 256 + u];
#pragma unroll
    for (int j = 0; j < 14; ++j) {
      float a = row[2 * j];
      float b = (2 * j + 1 < 27) ? row[2 * j + 1] : 0.f;
      wih[g][j] = pk(a, b);
    }
  }
#pragma unroll 1
  for (int j = u; j < 896; j += 256) {        // stage 64 rows of x
    int row = j / 14, c2 = j - 14 * row;
    const float* xr = x + ((size_t)(b0 + row) * 512 + t) * 27;
    float a = xr[2 * c2];
    float bb = (2 * c2 + 1 < 27) ? xr[2 * c2 + 1] : 0.f;
    sX[row][c2] = pk(a, bb);
  }
  __syncthreads();
  uint2* Pout = (uint2*)(ws + WS_P_OFF);
#pragma unroll 2
  for (int p = 0; p < 64; ++p) {
    float a0 = bias[0], a1 = bias[1], a2 = bias[2], a3 = bias[3];
#pragma unroll
    for (int j = 0; j < 14; ++j) {
      h2t xx = bc2(sX[p][j]);
      a0 = fdot2f(bc2(wih[0][j]), xx, a0);
      a1 = fdot2f(bc2(wih[1][j]), xx, a1);
      a2 = fdot2f(bc2(wih[2][j]), xx, a2);
      a3 = fdot2f(bc2(wih[3][j]), xx, a3);
    }
    uint2 o; o.x = pk(a0, a1); o.y = pk(a2, a3);
    Pout[((size_t)t * 128 + (b0 + p)) * 256 + u] = o;
  }
}

// Persistent LSTM scan. grid=128 (one block per batch element), 512 threads.
// Static LDS 86 KB > 80 KB -> compiler budgets 1 blk/CU, 2 waves/SIMD,
// 256 arch VGPRs. Thread v: half=v>>8 (K-half), u=v&255 (hidden unit).
__global__ __launch_bounds__(512, 2) void scan_k(
    const unsigned char* __restrict__ ws, const float* __restrict__ W_fc,
    const float* __restrict__ b_fc, float* __restrict__ out) {
  __shared__ u32x4 sWq[10 * 512];              // 81,920 B LDS-resident weights
  __shared__ u32x4 sHq[2][32];                 // h double buffer (128 h2)
  __shared__ float4 sAcc[256];                 // high->low partial exchange
  __shared__ float sHF[256];                   // final h fp32 for head
  const int v = threadIdx.x;
  const int b = blockIdx.x;
  const int half = v >> 8;
  const int u = v & 255;

  // --- tier 1: VGPR-resident weights (52 quads = 208 arch regs) ---
  u32x4 wr[52];
  {
    const u32x4* wsc = (const u32x4*)(ws + WS_WSCAN_OFF);
#pragma unroll
    for (int f = 0; f < 52; ++f) wr[f] = wsc[f * 512 + v];
  }
  // --- tier 2: LDS-resident weights (10 quads = 80 KB) ---
  {
    const u32x4* wld = (const u32x4*)(ws + WS_WLDS_OFF);
#pragma unroll
    for (int fl = 0; fl < 10; ++fl) sWq[fl * 512 + v] = wld[fl * 512 + v];
  }
  const u32x4* wstr = (const u32x4*)(ws + WS_WSTR_OFF);

  if (v < 64) {
    u32x4 z = {0u, 0u, 0u, 0u};
    ((u32x4*)sHq)[v] = z;                      // both h buffers = 0
  }
  const uint2* Pbuf = (const uint2*)(ws + WS_P_OFF);
  uint2 pP = make_uint2(0u, 0u);
  if (half == 0) pP = Pbuf[(size_t)b * 256 + u];
  float c = 0.f, hval = 0.f;
  __syncthreads();

#pragma unroll 1
  for (int t = 0; t < 512; ++t) {
    // --- tier 3: streamed weights (2 quads, 16 KB region, L1-resident) ---
    u32x4 tw0 = wstr[0 * 512 + v];
    u32x4 tw1 = wstr[1 * 512 + v];

    const u32x4* rd = &sHq[t & 1][half << 4];
    float acc0 = 0.f, acc1 = 0.f, acc2 = 0.f, acc3 = 0.f;
#pragma unroll
    for (int q = 0; q < 13; ++q) {             // f = 4q+g < 52: VGPR tier
      u32x4 hq = rd[q];
      acc0 = dot4(wr[q * 4 + 0], hq, acc0);
      acc1 = dot4(wr[q * 4 + 1], hq, acc1);
      acc2 = dot4(wr[q * 4 + 2], hq, acc2);
      acc3 = dot4(wr[q * 4 + 3], hq, acc3);
    }
    {  // q=13: f=52..55 LDS
      u32x4 hq = rd[13];
      acc0 = dot4(sWq[0 * 512 + v], hq, acc0);
      acc1 = dot4(sWq[1 * 512 + v], hq, acc1);
      acc2 = dot4(sWq[2 * 512 + v], hq, acc2);
      acc3 = dot4(sWq[3 * 512 + v], hq, acc3);
    }
    {  // q=14: f=56..59 LDS
      u32x4 hq = rd[14];
      acc0 = dot4(sWq[4 * 512 + v], hq, acc0);
      acc1 = dot4(sWq[5 * 512 + v], hq, acc1);
      acc2 = dot4(sWq[6 * 512 + v], hq, acc2);
      acc3 = dot4(sWq[7 * 512 + v], hq, acc3);
    }
    {  // q=15: f=60,61 LDS; f=62,63 streamed
      u32x4 hq = rd[15];
      acc0 = dot4(sWq[8 * 512 + v], hq, acc0);
      acc1 = dot4(sWq[9 * 512 + v], hq, acc1);
      acc2 = dot4(tw0, hq, acc2);
      acc3 = dot4(tw1, hq, acc3);
    }

    uint2 pPn = pP;
    if (half) {
      sAcc[u] = make_float4(acc0, acc1, acc2, acc3);
    } else {
      int tn = (t < 511) ? (t + 1) : 511;
      pPn = Pbuf[((size_t)tn * 128 + b) * 256 + u];
    }
    __syncthreads();                           // sAcc visible; sH reads done

    if (!half) {
      float4 oth = sAcc[u];
      h2t p01 = bc2(pP.x), p23 = bc2(pP.y);
      float gi = acc0 + oth.x + (float)p01[0];
      float gf = acc1 + oth.y + (float)p01[1];
      float gg = acc2 + oth.z + (float)p23[0];
      float go = acc3 + oth.w + (float)p23[1];
      c = sigmf_(gf) * c + sigmf_(gi) * tanhf_(gg);
      hval = sigmf_(go) * tanhf_(c);
      ((_Float16*)(&sHq[(t + 1) & 1][0]))[u] = (_Float16)hval;
    }
    pP = pPn;
    __syncthreads();                           // h_{t+1} visible
  }

  // --- classifier head on final h ---
  if (!half) sHF[u] = hval;
  __syncthreads();
  if (v < 128) {
    const float4* wrow = (const float4*)(W_fc + (size_t)v * 256);
    float a = b_fc[v];
#pragma unroll 8
    for (int q = 0; q < 64; ++q) {
      float4 w = wrow[q];
      float4 hh = ((const float4*)sHF)[q];
      a += w.x * hh.x + w.y * hh.y + w.z * hh.z + w.w * hh.w;
    }
    out[(size_t)b * 128 + v] = a;
  }
}

extern "C" void kernel_launch(void* const* d_in, const int* in_sizes, int n_in,
                              void* d_out, int out_size, void* d_ws,
                              size_t ws_size, hipStream_t stream) {
  const float* x    = (const float*)d_in[0];
  // d_in[1] = input_lengths: unused by the reference
  const float* W_ih = (const float*)d_in[2];
  const float* W_hh = (const float*)d_in[3];
  const float* b_ih = (const float*)d_in[4];
  const float* b_hh = (const float*)d_in[5];
  // d_in[6] = W_xi, d_in[7] = b_xi: dead code in the reference
  const float* W_fc = (const float*)d_in[8];
  const float* b_fc = (const float*)d_in[9];
  unsigned char* ws = (unsigned char*)d_ws;

  if (ws_size < WS_NEED) return;  // signature: output stays poisoned

  prep_w<<<512, 256, 0, stream>>>(W_hh, ws);
  prep_p<<<1024, 256, 0, stream>>>(x, W_ih, b_ih, b_hh, ws);
  scan_k<<<128, 512, 0, stream>>>(ws, W_fc, b_fc, (float*)d_out);
}